// Round 1
// baseline (37.447 us; speedup 1.0000x reference)
//
#include <hip/hip_runtime.h>

#define N1 96     // n1 = m1 = 96
#define NV 95     // n = m = 95
#define LP 100    // padded LDS row stride (floats); 16B-aligned rows
#define SINK_ITERS 10

// ---------------------------------------------------------------------------
// K1: build cost tables, init S0 = exp(-0.5 c), run 10 sinkhorn iterations
// (cumulative row/col scale trick: S_final = diag(R) S0 diag(C)), write S to
// ws, write f-table to ws, compute cv = c.v and diagcorr; d_out = cv - 0.5*diag
// ---------------------------------------------------------------------------
__global__ __launch_bounds__(1024)
void ged_k1(const float* __restrict__ nw, const float* __restrict__ ew,
            const int* __restrict__ Ag1, const int* __restrict__ Ag2,
            const int* __restrict__ lab1g, const int* __restrict__ lab2g,
            float* __restrict__ Sg, float* __restrict__ fg,
            float* __restrict__ outp)
{
    __shared__ float S0[N1 * LP];
    __shared__ float S0T[N1 * LP];
    __shared__ float R[N1], C[N1];
    __shared__ float part[N1 * 9];        // padded 9 to kill bank conflicts
    __shared__ float nc[100];             // node_costs 10x10
    __shared__ float cn[46], ce[4];
    __shared__ float ftab[16];            // f(a,b) 4x4
    __shared__ int l1[N1], l2[N1], a1d[N1], a2d[N1];
    __shared__ float wred[16];
    __shared__ float nid_s;

    const int tid = threadIdx.x;

    // ---- load weights (parallel, relu'd) ----
    if (tid < 46) cn[tid] = fmaxf(nw[tid], 0.f);
    if (tid >= 64 && tid < 68) ce[tid - 64] = fmaxf(ew[tid - 64], 0.f);
    if (tid >= 128 && tid < 128 + N1) {
        int t = tid - 128;
        l1[t]  = (t < NV) ? lab1g[t] : 0;
        l2[t]  = (t < NV) ? lab2g[t] : 0;
        a1d[t] = (t < NV) ? Ag1[t * NV + t] : 0;   // A1 diagonal (padded row/col = 0)
        a2d[t] = (t < NV) ? Ag2[t * NV + t] : 0;
        R[t] = 1.f; C[t] = 1.f;
    }
    __syncthreads();

    // ---- node_costs: fill symmetric 10x10 from 45 upper-tri values ----
    if (tid < 45) {
        int i = 0, rem = tid;
        while (rem >= 9 - i) { rem -= 9 - i; ++i; }
        int j = i + 1 + rem;
        float v = cn[tid];
        nc[i * 10 + j] = v; nc[j * 10 + i] = v;
    }
    if (tid >= 45 && tid < 55) nc[(tid - 45) * 11] = 0.f;   // diagonal
    if (tid == 0) {
        nid_s = cn[45];
        float e01 = ce[0], e02 = ce[1], e12 = ce[2], eid = ce[3];
        // f(a,b): a,b in {0..3}; 0 = no edge
        ftab[0] = 0.f;  ftab[1] = eid;  ftab[2] = eid;  ftab[3] = eid;
        ftab[4] = eid;  ftab[5] = 0.f;  ftab[6] = e01;  ftab[7] = e02;
        ftab[8] = eid;  ftab[9] = e01;  ftab[10] = 0.f; ftab[11] = e12;
        ftab[12] = eid; ftab[13] = e02; ftab[14] = e12; ftab[15] = 0.f;
    }
    __syncthreads();

    // ---- init S0 = exp(-0.5 * c), plus transposed copy ----
    for (int idx = tid; idx < N1 * N1; idx += 1024) {
        int u = idx / N1, v = idx - u * N1;
        float cuv;
        if (u < NV && v < NV) cuv = nc[l1[u] * 10 + l2[v]];
        else cuv = (u == NV && v == NV) ? 0.f : nid_s;
        float s = expf(-0.5f * cuv);
        S0[u * LP + v] = s;
        S0T[v * LP + u] = s;
    }
    __syncthreads();

    // ---- sinkhorn: R[u] = 1/sum_v S0[u,v]*C[v] (u<95); C[v] = 1/sum_u R[u]*S0[u,v] ----
    for (int it = 0; it < SINK_ITERS; ++it) {
        if (tid < 768) {                       // row pass: 8 chunks of 12 per row
            int u = tid >> 3, p = tid & 7;
            const float4* s4 = (const float4*)&S0[u * LP + p * 12];
            const float4* c4 = (const float4*)&C[p * 12];
            float acc = 0.f;
            #pragma unroll
            for (int q = 0; q < 3; ++q) {
                float4 a = s4[q], b = c4[q];
                acc += a.x * b.x + a.y * b.y + a.z * b.z + a.w * b.w;
            }
            part[u * 9 + p] = acc;
        }
        __syncthreads();
        if (tid < N1) {
            float s = 0.f;
            #pragma unroll
            for (int p = 0; p < 8; ++p) s += part[tid * 9 + p];
            R[tid] = (tid == NV) ? 1.f : 1.f / s;
        }
        __syncthreads();
        if (tid < 768) {                       // col pass on transposed copy
            int v = tid >> 3, p = tid & 7;
            const float4* s4 = (const float4*)&S0T[v * LP + p * 12];
            const float4* r4 = (const float4*)&R[p * 12];
            float acc = 0.f;
            #pragma unroll
            for (int q = 0; q < 3; ++q) {
                float4 a = s4[q], b = r4[q];
                acc += a.x * b.x + a.y * b.y + a.z * b.z + a.w * b.w;
            }
            part[v * 9 + p] = acc;
        }
        __syncthreads();
        if (tid < N1) {
            float s = 0.f;
            #pragma unroll
            for (int p = 0; p < 8; ++p) s += part[tid * 9 + p];
            C[tid] = (tid == NV) ? 1.f : 1.f / s;
        }
        __syncthreads();
    }

    // ---- write final S, f-table; accumulate cv and diag correction ----
    float cv_part = 0.f, dg_part = 0.f;
    for (int idx = tid; idx < N1 * N1; idx += 1024) {
        int u = idx / N1, v = idx - u * N1;
        float s = S0[u * LP + v] * R[u] * C[v];
        Sg[idx] = s;
        float cuv;
        if (u < NV && v < NV) cuv = nc[l1[u] * 10 + l2[v]];
        else cuv = (u == NV && v == NV) ? 0.f : nid_s;
        cv_part += cuv * s;
        dg_part += s * s * ftab[a1d[u] * 4 + a2d[v]];
    }
    if (tid < 16) fg[tid] = ftab[tid];

    float x = cv_part - 0.5f * dg_part;
    #pragma unroll
    for (int off = 32; off > 0; off >>= 1) x += __shfl_down(x, off, 64);
    if ((tid & 63) == 0) wred[tid >> 6] = x;
    __syncthreads();
    if (tid == 0) {
        float s = 0.f;
        #pragma unroll
        for (int w = 0; w < 16; ++w) s += wred[w];
        outp[0] = s;   // overwrite each launch (d_out is poisoned once)
    }
}

// ---------------------------------------------------------------------------
// K2: Z_b[k,i] = sum_l 1[A2e[k,l]==b] * S[i,l]   (b = 0..3, packed float4)
// ---------------------------------------------------------------------------
__global__ __launch_bounds__(256)
void ged_k2(const int* __restrict__ Ag2, const float* __restrict__ Sg,
            float4* __restrict__ Z4)
{
    int gid = blockIdx.x * 256 + threadIdx.x;   // 0..9215
    int k = gid / N1, i = gid - k * N1;
    const float* srow = Sg + i * N1;
    float z0 = 0.f, z1 = 0.f, z2 = 0.f, z3 = 0.f;
    if (k < NV) {
        const int* arow = Ag2 + k * NV;
        for (int l = 0; l < NV; ++l) {
            float s = srow[l];
            int lab = arow[l];
            z0 += (lab == 0) ? s : 0.f;
            z1 += (lab == 1) ? s : 0.f;
            z2 += (lab == 2) ? s : 0.f;
            z3 += (lab == 3) ? s : 0.f;
        }
        z0 += srow[NV];           // padded column l=95 has label 0
    } else {
        for (int l = 0; l < N1; ++l) z0 += srow[l];   // padded row k=95
    }
    Z4[k * N1 + i] = make_float4(z0, z1, z2, z3);
}

// ---------------------------------------------------------------------------
// K3: quad_full = sum_{i,j,b} f(A1e[i,j], b) * sum_k S[j,k] * Z_b[k,i];
// block-reduce and atomicAdd 0.5*quad into d_out.
// ---------------------------------------------------------------------------
__global__ __launch_bounds__(256)
void ged_k3(const int* __restrict__ Ag1, const float* __restrict__ Sg,
            const float* __restrict__ fg, const float4* __restrict__ Z4,
            float* __restrict__ outp)
{
    int gid = blockIdx.x * 256 + threadIdx.x;   // 0..9215
    int j = gid / N1, i = gid - j * N1;
    int a = (i < NV && j < NV) ? Ag1[i * NV + j] : 0;
    const float* srow = Sg + j * N1;
    float d0 = 0.f, d1 = 0.f, d2 = 0.f, d3 = 0.f;
    for (int k = 0; k < N1; ++k) {
        float s = srow[k];
        float4 z = Z4[k * N1 + i];
        d0 += s * z.x; d1 += s * z.y; d2 += s * z.z; d3 += s * z.w;
    }
    float4 fv = ((const float4*)fg)[a];
    float x = 0.5f * (fv.x * d0 + fv.y * d1 + fv.z * d2 + fv.w * d3);
    #pragma unroll
    for (int off = 32; off > 0; off >>= 1) x += __shfl_down(x, off, 64);
    __shared__ float wsum[4];
    if ((threadIdx.x & 63) == 0) wsum[threadIdx.x >> 6] = x;
    __syncthreads();
    if (threadIdx.x == 0) atomicAdd(outp, wsum[0] + wsum[1] + wsum[2] + wsum[3]);
}

extern "C" void kernel_launch(void* const* d_in, const int* in_sizes, int n_in,
                              void* d_out, int out_size, void* d_ws, size_t ws_size,
                              hipStream_t stream)
{
    (void)in_sizes; (void)n_in; (void)out_size; (void)ws_size;
    const float* nw  = (const float*)d_in[0];
    const float* ew  = (const float*)d_in[1];
    const int*   Ag1 = (const int*)d_in[2];
    const int*   Ag2 = (const int*)d_in[3];
    const int*   l1  = (const int*)d_in[4];
    const int*   l2  = (const int*)d_in[5];
    float* outp = (float*)d_out;

    // ws layout (floats): S[9216] | ftab[16] | Z[9216*4]
    float*  Sg = (float*)d_ws;
    float*  fg = Sg + 9216;
    float4* Z4 = (float4*)(fg + 16);   // byte offset 36928, 16B-aligned

    hipLaunchKernelGGL(ged_k1, dim3(1), dim3(1024), 0, stream,
                       nw, ew, Ag1, Ag2, l1, l2, Sg, fg, outp);
    hipLaunchKernelGGL(ged_k2, dim3(36), dim3(256), 0, stream, Ag2, Sg, Z4);
    hipLaunchKernelGGL(ged_k3, dim3(36), dim3(256), 0, stream,
                       Ag1, Sg, fg, Z4, outp);
}

// Round 2
// 14.756 us; speedup vs baseline: 2.5377x; 2.5377x over previous
//
#include <hip/hip_runtime.h>

#define NV 95           // n = m = 95
#define SINK_ITERS 10

// ---------------------------------------------------------------------------
// Entire GED forward in ONE block.
//
// Key identity: S0[u,v] = exp(-0.5*c(a_u, b_v)) depends only on the label
// types a_u = lab1[u] (10 = border row 95), b_v = lab2[v]. Sinkhorn scales
// are constant within a label type, so sinkhorn runs EXACTLY on an 11x11
// compressed matrix weighted by label counts. Both scales are "fresh":
//   R[a] = 1/sum_b cnt2[b]*E0[a,b]*C[b]   (R[10] forced 1)
//   C[b] = 1/sum_a cnt1[a]*E0[a,b]*R[a]   (C[10] forced 1)
// Final S[u,v] = T[a_u][b_v],  T = E0 * R ⊗ C.
//
// quad = sum_{i,j,k,l} f(A1[i,j],A2[k,l]) S[j,k] S[i,l]
//      = sum_{e1,e2} f[e1][e2] sum_{a,b} Q1[e1][a][b] * R2[e2][a][b]
//   Q1[e1][a][b] = sum_{a'} P1[e1][a][a'] T[a'][b]
//   R2[e2][a][b] = sum_{b'} P2[e2][b][b'] T[a][b']
//   P1[e][a][a'] = #{(i,j): A1e[i,j]=e, labs=(a,a')}   (e=0 by complement)
// diag corr = sum f[e1][e2] H1[e1][a] H2[e2][b] T[a][b]^2  (H = diag hists)
// cv = sum cnt1[a] cnt2[b] c(a,b) T[a][b]
// out = cv + 0.5*(quad - diag)
// ---------------------------------------------------------------------------
__global__ __launch_bounds__(1024)
void ged_all(const float* __restrict__ nw, const float* __restrict__ ew,
             const int* __restrict__ Ag1, const int* __restrict__ Ag2,
             const int* __restrict__ lab1g, const int* __restrict__ lab2g,
             float* __restrict__ outp)
{
    __shared__ float cn[46], ce[4];
    __shared__ float nc[100];            // node_costs 10x10
    __shared__ float ftab[16];           // f(e1,e2) 4x4
    __shared__ float nids;
    __shared__ int   labs1[96], labs2[96];
    __shared__ int   cnt1[12], cnt2[12];
    __shared__ int   P1h[3 * 121], P2h[3 * 121];   // e = 1..3 histograms
    __shared__ int   H1[4 * 12], H2[4 * 12];       // diagonal hists
    __shared__ float E0s[11 * 12];       // exp(-0.5 c), padded stride 12
    __shared__ float Rs[12], Cs[12];
    __shared__ float Ts[11 * 12];
    __shared__ float P1f[4 * 121], P2f[4 * 121];
    __shared__ float Q1s[4 * 132], R2s[4 * 132];
    __shared__ float wred[16];

    const int tid = threadIdx.x;

    // ---------------- S0: raw loads + zero hists ----------------
    if (tid < 46) cn[tid] = fmaxf(nw[tid], 0.f);
    if (tid >= 64 && tid < 68) ce[tid - 64] = fmaxf(ew[tid - 64], 0.f);
    if (tid >= 128 && tid < 224) { int t = tid - 128; labs1[t] = (t < NV) ? lab1g[t] : 10; }
    if (tid >= 256 && tid < 352) { int t = tid - 256; labs2[t] = (t < NV) ? lab2g[t] : 10; }
    for (int i = tid; i < 363; i += 1024) { P1h[i] = 0; P2h[i] = 0; }
    if (tid < 48) { H1[tid] = 0; H2[tid] = 0; }
    if (tid < 12) { cnt1[tid] = 0; cnt2[tid] = 0; }
    __syncthreads();

    // ---------------- S1: tables, counts, histograms ----------------
    if (tid < 45) {          // node_costs upper-tri -> symmetric
        int i = 0, rem = tid;
        while (rem >= 9 - i) { rem -= 9 - i; ++i; }
        int j = i + 1 + rem;
        float v = cn[tid];
        nc[i * 10 + j] = v; nc[j * 10 + i] = v;
    }
    if (tid >= 45 && tid < 55) nc[(tid - 45) * 11] = 0.f;
    if (tid == 0) {
        nids = cn[45];
        float e01 = ce[0], e02 = ce[1], e12 = ce[2], eid = ce[3];
        ftab[0] = 0.f;  ftab[1] = eid;  ftab[2] = eid;  ftab[3] = eid;
        ftab[4] = eid;  ftab[5] = 0.f;  ftab[6] = e01;  ftab[7] = e02;
        ftab[8] = eid;  ftab[9] = e01;  ftab[10] = 0.f; ftab[11] = e12;
        ftab[12] = eid; ftab[13] = e02; ftab[14] = e12; ftab[15] = 0.f;
    }
    if (tid == 1) { cnt1[10] = 1; cnt2[10] = 1; }          // border types
    if (tid >= 64 && tid < 64 + NV)   atomicAdd(&cnt1[labs1[tid - 64]], 1);
    if (tid >= 192 && tid < 192 + NV) atomicAdd(&cnt2[labs2[tid - 192]], 1);
    if (tid >= 320 && tid < 416) {   // A1 diagonal hist (u=95 -> e=0, a=10)
        int u = tid - 320;
        int e = (u < NV) ? Ag1[u * 96] : 0;     // u*95+u = u*96
        atomicAdd(&H1[e * 12 + labs1[u]], 1);
    }
    if (tid >= 448 && tid < 544) {
        int u = tid - 448;
        int e = (u < NV) ? Ag2[u * 96] : 0;
        atomicAdd(&H2[e * 12 + labs2[u]], 1);
    }
    for (int idx = tid; idx < NV * NV; idx += 1024) {   // main hist scans
        int i = idx / NV, j = idx - i * NV;
        int v1 = Ag1[idx];
        if (v1) atomicAdd(&P1h[(v1 - 1) * 121 + labs1[i] * 11 + labs1[j]], 1);
        int v2 = Ag2[idx];
        if (v2) atomicAdd(&P2h[(v2 - 1) * 121 + labs2[i] * 11 + labs2[j]], 1);
    }
    __syncthreads();

    // ---------------- S2: E0 table + float hists (e=0 by complement) ----
    if (tid < 121) {
        int a = tid / 11, b = tid - a * 11;
        float c;
        if (a < 10 && b < 10) c = nc[a * 10 + b];
        else c = (a == 10 && b == 10) ? 0.f : nids;
        E0s[a * 12 + b] = expf(-0.5f * c);
    }
    if (tid < 484) {
        int e = tid / 121, aa = tid - e * 121;
        float v;
        if (e == 0) v = (float)(cnt1[aa / 11] * cnt1[aa % 11])
                        - (float)(P1h[aa] + P1h[121 + aa] + P1h[242 + aa]);
        else v = (float)P1h[(e - 1) * 121 + aa];
        P1f[tid] = v;
    }
    if (tid >= 512 && tid < 996) {
        int t = tid - 512;
        int e = t / 121, aa = t - e * 121;
        float v;
        if (e == 0) v = (float)(cnt2[aa / 11] * cnt2[aa % 11])
                        - (float)(P2h[aa] + P2h[121 + aa] + P2h[242 + aa]);
        else v = (float)P2h[(e - 1) * 121 + aa];
        P2f[t] = v;
    }
    __syncthreads();

    // ---------------- S3: 11x11 sinkhorn, one wave, shuffle-only ----------
    if (tid < 64) {
        int l = tid;
        int ll = (l < 11) ? l : 0;       // clamp so lanes 11..63 hold valid data
        float ecrow[11], eccol[11];
        #pragma unroll
        for (int b = 0; b < 11; ++b) ecrow[b] = E0s[ll * 12 + b] * (float)cnt2[b];
        #pragma unroll
        for (int a = 0; a < 11; ++a) eccol[a] = E0s[a * 12 + ll] * (float)cnt1[a];
        float Rv = 1.f, Cv = 1.f;
        for (int it = 0; it < SINK_ITERS; ++it) {
            float s = 0.f;
            #pragma unroll
            for (int b = 0; b < 11; ++b) s += ecrow[b] * __shfl(Cv, b, 64);
            Rv = (l == 10) ? 1.f : 1.f / s;
            float s2 = 0.f;
            #pragma unroll
            for (int a = 0; a < 11; ++a) s2 += eccol[a] * __shfl(Rv, a, 64);
            Cv = (l == 10) ? 1.f : 1.f / s2;
        }
        if (l < 11) { Rs[l] = Rv; Cs[l] = Cv; }
    }
    __syncthreads();

    // ---------------- S4: T = E0 * R x C ----------------
    if (tid < 121) {
        int a = tid / 11, b = tid - a * 11;
        Ts[a * 12 + b] = E0s[a * 12 + b] * Rs[a] * Cs[b];
    }
    __syncthreads();

    // ---------------- S5: Q1 / R2 contractions ----------------
    if (tid < 484) {
        int e = tid / 121, ab = tid - e * 121, a = ab / 11, b = ab - a * 11;
        float s = 0.f;
        #pragma unroll
        for (int a2 = 0; a2 < 11; ++a2) s += P1f[e * 121 + a * 11 + a2] * Ts[a2 * 12 + b];
        Q1s[e * 132 + a * 12 + b] = s;
    }
    if (tid >= 512 && tid < 996) {
        int t = tid - 512;
        int e = t / 121, ab = t - e * 121, a = ab / 11, b = ab - a * 11;
        float s = 0.f;
        #pragma unroll
        for (int b2 = 0; b2 < 11; ++b2) s += P2f[e * 121 + b * 11 + b2] * Ts[a * 12 + b2];
        R2s[e * 132 + a * 12 + b] = s;
    }
    __syncthreads();

    // ---------------- S6: final scalar ----------------
    float x = 0.f;
    if (tid < 968) {           // 2 of the 1936 (e1,e2,a,b) terms each
        #pragma unroll
        for (int r = 0; r < 2; ++r) {
            int t = tid + r * 968;
            int p = t / 121, ab = t - p * 121;
            int e1 = p >> 2, e2 = p & 3;
            int a = ab / 11, b = ab - a * 11;
            float f  = ftab[p];
            float tt = Ts[a * 12 + b];
            x += 0.5f * f * (Q1s[e1 * 132 + a * 12 + b] * R2s[e2 * 132 + a * 12 + b]
                             - (float)H1[e1 * 12 + a] * (float)H2[e2 * 12 + b] * tt * tt);
        }
    }
    if (tid < 121) {           // cv = c . v
        int a = tid / 11, b = tid - a * 11;
        float c;
        if (a < 10 && b < 10) c = nc[a * 10 + b];
        else c = (a == 10 && b == 10) ? 0.f : nids;
        x += (float)(cnt1[a] * cnt2[b]) * c * Ts[a * 12 + b];
    }
    #pragma unroll
    for (int off = 32; off > 0; off >>= 1) x += __shfl_down(x, off, 64);
    if ((tid & 63) == 0) wred[tid >> 6] = x;
    __syncthreads();
    if (tid == 0) {
        float s = 0.f;
        #pragma unroll
        for (int w = 0; w < 16; ++w) s += wred[w];
        outp[0] = s;
    }
}

extern "C" void kernel_launch(void* const* d_in, const int* in_sizes, int n_in,
                              void* d_out, int out_size, void* d_ws, size_t ws_size,
                              hipStream_t stream)
{
    (void)in_sizes; (void)n_in; (void)out_size; (void)d_ws; (void)ws_size;
    const float* nw  = (const float*)d_in[0];
    const float* ew  = (const float*)d_in[1];
    const int*   Ag1 = (const int*)d_in[2];
    const int*   Ag2 = (const int*)d_in[3];
    const int*   l1  = (const int*)d_in[4];
    const int*   l2  = (const int*)d_in[5];
    hipLaunchKernelGGL(ged_all, dim3(1), dim3(1024), 0, stream,
                       nw, ew, Ag1, Ag2, l1, l2, (float*)d_out);
}

// Round 3
// 14.399 us; speedup vs baseline: 2.6007x; 1.0248x over previous
//
#include <hip/hip_runtime.h>

#define NV 95           // n = m = 95
#define SINK_ITERS 10

// One-block GED forward, label-compressed (see R2 derivation), restructured:
//  Ph0: issue ALL global loads (A as int4 into regs, labels, weights, diag)
//  Ph1: tables + label counts + diag hists
//  Ph2: WAVE-SPLIT — wave0: 11x11 sinkhorn (own expf); waves1-2: E0 table;
//       waves3-15: histogram atomics from registered A data
//  Ph3: Q1/R2 contractions (e=0 complement + T folded in)
//  Ph4: final scalar reduction
__global__ __launch_bounds__(1024)
void ged_all(const float* __restrict__ nw, const float* __restrict__ ew,
             const int* __restrict__ Ag1, const int* __restrict__ Ag2,
             const int* __restrict__ lab1g, const int* __restrict__ lab2g,
             float* __restrict__ outp)
{
    __shared__ float cn[46], ce[4];
    __shared__ float nc[100];            // node_costs 10x10
    __shared__ float ftab[16];           // f(e1,e2) 4x4
    __shared__ float nids;
    __shared__ int   labs1[96], labs2[96];
    __shared__ int   cnt1[12], cnt2[12];
    __shared__ int   P1h[3 * 121], P2h[3 * 121];   // e = 1..3 histograms
    __shared__ int   H1[4 * 12], H2[4 * 12];       // diagonal hists
    __shared__ float E0s[11 * 12];       // exp(-0.5 c), stride 12
    __shared__ float Rs[12], Cs[12];
    __shared__ float Q1s[4 * 132], R2s[4 * 132];
    __shared__ float wred[16];

    const int tid = threadIdx.x;

    // ================= Ph0: issue all global loads =================
    // main A data: 9025 ints = 2256 int4 slots + 1 remainder element
    const int4* A1_4 = (const int4*)Ag1;
    const int4* A2_4 = (const int4*)Ag2;
    int4 a1r[3], a2r[3];
    const bool scanner = (tid >= 192);
    const int  sbase = tid - 192;                 // 0..831
    if (scanner) {
        #pragma unroll
        for (int r = 0; r < 3; ++r) {
            int slot = sbase + r * 832;
            if (slot < 2256) { a1r[r] = A1_4[slot]; a2r[r] = A2_4[slot]; }
        }
    }
    int rem1 = 0, rem2 = 0;
    if (tid == 1023) { rem1 = Ag1[9024]; rem2 = Ag2[9024]; }
    int d1 = 0, d2 = 0;
    if (tid >= 320 && tid < 416) { int u = tid - 320; d1 = (u < NV) ? Ag1[u * 96] : 0; }
    if (tid >= 448 && tid < 544) { int u = tid - 448; d2 = (u < NV) ? Ag2[u * 96] : 0; }

    if (tid < 46) cn[tid] = fmaxf(nw[tid], 0.f);
    if (tid >= 64 && tid < 68) ce[tid - 64] = fmaxf(ew[tid - 64], 0.f);
    if (tid >= 128 && tid < 224) { int t = tid - 128; labs1[t] = (t < NV) ? lab1g[t] : 10; }
    if (tid >= 256 && tid < 352) { int t = tid - 256; labs2[t] = (t < NV) ? lab2g[t] : 10; }
    for (int i = tid; i < 363; i += 1024) { P1h[i] = 0; P2h[i] = 0; }
    if (tid < 48) { H1[tid] = 0; H2[tid] = 0; }
    if (tid < 12) { cnt1[tid] = 0; cnt2[tid] = 0; }
    __syncthreads();   // ---- barrier A ----

    // ================= Ph1: tables, counts, diag hists =================
    if (tid < 45) {
        int i = 0, rem = tid;
        while (rem >= 9 - i) { rem -= 9 - i; ++i; }
        int j = i + 1 + rem;
        float v = cn[tid];
        nc[i * 10 + j] = v; nc[j * 10 + i] = v;
    }
    if (tid >= 45 && tid < 55) nc[(tid - 45) * 11] = 0.f;
    if (tid == 0) {
        nids = cn[45];
        float e01 = ce[0], e02 = ce[1], e12 = ce[2], eid = ce[3];
        ftab[0] = 0.f;  ftab[1] = eid;  ftab[2] = eid;  ftab[3] = eid;
        ftab[4] = eid;  ftab[5] = 0.f;  ftab[6] = e01;  ftab[7] = e02;
        ftab[8] = eid;  ftab[9] = e01;  ftab[10] = 0.f; ftab[11] = e12;
        ftab[12] = eid; ftab[13] = e02; ftab[14] = e12; ftab[15] = 0.f;
    }
    if (tid == 1) { cnt1[10] = 1; cnt2[10] = 1; }
    if (tid >= 64 && tid < 64 + NV)   atomicAdd(&cnt1[labs1[tid - 64]], 1);
    if (tid >= 192 && tid < 192 + NV) atomicAdd(&cnt2[labs2[tid - 192]], 1);
    if (tid >= 320 && tid < 416) atomicAdd(&H1[d1 * 12 + labs1[tid - 320]], 1);
    if (tid >= 448 && tid < 544) atomicAdd(&H2[d2 * 12 + labs2[tid - 448]], 1);
    __syncthreads();   // ---- barrier B ----

    // ================= Ph2: wave-split =================
    if (tid < 64) {
        // ---- 11x11 sinkhorn, one wave, shuffle-only; own expf terms ----
        int l = tid;
        int ll = (l < 11) ? l : 0;
        float nid_l = nids;
        float ecrow[11], eccol[11];
        #pragma unroll
        for (int b = 0; b < 11; ++b) {
            float c = (ll < 10 && b < 10) ? nc[ll * 10 + b]
                     : ((ll == 10 && b == 10) ? 0.f : nid_l);
            ecrow[b] = expf(-0.5f * c) * (float)cnt2[b];
        }
        #pragma unroll
        for (int a = 0; a < 11; ++a) {
            float c = (a < 10 && ll < 10) ? nc[a * 10 + ll]
                     : ((a == 10 && ll == 10) ? 0.f : nid_l);
            eccol[a] = expf(-0.5f * c) * (float)cnt1[a];
        }
        float Rv = 1.f, Cv = 1.f;
        for (int it = 0; it < SINK_ITERS; ++it) {
            float s = 0.f;
            #pragma unroll
            for (int b = 0; b < 11; ++b) s += ecrow[b] * __shfl(Cv, b, 64);
            Rv = (l == 10) ? 1.f : 1.f / s;
            float s2 = 0.f;
            #pragma unroll
            for (int a = 0; a < 11; ++a) s2 += eccol[a] * __shfl(Rv, a, 64);
            Cv = (l == 10) ? 1.f : 1.f / s2;
        }
        if (l < 11) { Rs[l] = Rv; Cs[l] = Cv; }
    } else if (tid < 185) {
        // ---- E0 table ----
        int t = tid - 64;
        int a = t / 11, b = t - a * 11;
        float c = (a < 10 && b < 10) ? nc[a * 10 + b]
                 : ((a == 10 && b == 10) ? 0.f : nids);
        E0s[a * 12 + b] = expf(-0.5f * c);
    } else if (scanner) {
        // ---- histogram atomics from registered A data ----
        #pragma unroll
        for (int r = 0; r < 3; ++r) {
            int slot = sbase + r * 832;
            if (slot < 2256) {
                int base = slot * 4;
                int v1[4] = { a1r[r].x, a1r[r].y, a1r[r].z, a1r[r].w };
                int v2[4] = { a2r[r].x, a2r[r].y, a2r[r].z, a2r[r].w };
                #pragma unroll
                for (int q = 0; q < 4; ++q) {
                    int idx = base + q;
                    int i = idx / NV, j = idx - i * NV;
                    if (v1[q]) atomicAdd(&P1h[(v1[q] - 1) * 121 + labs1[i] * 11 + labs1[j]], 1);
                    if (v2[q]) atomicAdd(&P2h[(v2[q] - 1) * 121 + labs2[i] * 11 + labs2[j]], 1);
                }
            }
        }
        if (tid == 1023) {   // remainder element idx 9024 -> (94,94)
            if (rem1) atomicAdd(&P1h[(rem1 - 1) * 121 + labs1[94] * 11 + labs1[94]], 1);
            if (rem2) atomicAdd(&P2h[(rem2 - 1) * 121 + labs2[94] * 11 + labs2[94]], 1);
        }
    }
    __syncthreads();   // ---- barrier C ----

    // ================= Ph3: Q1 / R2 contractions =================
    // Q1[e][a][b] = Cs[b] * sum_a2 P1[e][a][a2] * E0[a2][b] * Rs[a2]
    // R2[e][a][b] = Rs[a] * sum_b2 P2[e][b][b2] * E0[a][b2] * Cs[b2]
    if (tid < 484) {
        int e = tid / 121, ab = tid - e * 121, a = ab / 11, b = ab - a * 11;
        float s = 0.f;
        #pragma unroll
        for (int a2 = 0; a2 < 11; ++a2) {
            int aa = a * 11 + a2;
            float p = (e == 0)
                ? (float)(cnt1[a] * cnt1[a2] - P1h[aa] - P1h[121 + aa] - P1h[242 + aa])
                : (float)P1h[(e - 1) * 121 + aa];
            s += p * E0s[a2 * 12 + b] * Rs[a2];
        }
        Q1s[e * 132 + a * 12 + b] = s * Cs[b];
    }
    if (tid >= 512 && tid < 996) {
        int t = tid - 512;
        int e = t / 121, ab = t - e * 121, a = ab / 11, b = ab - a * 11;
        float s = 0.f;
        #pragma unroll
        for (int b2 = 0; b2 < 11; ++b2) {
            int bb = b * 11 + b2;
            float p = (e == 0)
                ? (float)(cnt2[b] * cnt2[b2] - P2h[bb] - P2h[121 + bb] - P2h[242 + bb])
                : (float)P2h[(e - 1) * 121 + bb];
            s += p * E0s[a * 12 + b2] * Cs[b2];
        }
        R2s[e * 132 + a * 12 + b] = s * Rs[a];
    }
    __syncthreads();   // ---- barrier D ----

    // ================= Ph4: final scalar =================
    float x = 0.f;
    if (tid < 968) {     // 2 of 1936 (e1,e2,a,b) terms each
        #pragma unroll
        for (int r = 0; r < 2; ++r) {
            int t = tid + r * 968;
            int p = t / 121, ab = t - p * 121;
            int e1 = p >> 2, e2 = p & 3;
            int a = ab / 11, b = ab - a * 11;
            float f  = ftab[p];
            float tt = E0s[a * 12 + b] * Rs[a] * Cs[b];
            x += 0.5f * f * (Q1s[e1 * 132 + a * 12 + b] * R2s[e2 * 132 + a * 12 + b]
                             - (float)H1[e1 * 12 + a] * (float)H2[e2 * 12 + b] * tt * tt);
        }
    }
    if (tid < 121) {     // cv = c . v
        int a = tid / 11, b = tid - a * 11;
        float c = (a < 10 && b < 10) ? nc[a * 10 + b]
                 : ((a == 10 && b == 10) ? 0.f : nids);
        x += (float)(cnt1[a] * cnt2[b]) * c * E0s[a * 12 + b] * Rs[a] * Cs[b];
    }
    #pragma unroll
    for (int off = 32; off > 0; off >>= 1) x += __shfl_down(x, off, 64);
    if ((tid & 63) == 0) wred[tid >> 6] = x;
    __syncthreads();
    if (tid == 0) {
        float s = 0.f;
        #pragma unroll
        for (int w = 0; w < 16; ++w) s += wred[w];
        outp[0] = s;
    }
}

extern "C" void kernel_launch(void* const* d_in, const int* in_sizes, int n_in,
                              void* d_out, int out_size, void* d_ws, size_t ws_size,
                              hipStream_t stream)
{
    (void)in_sizes; (void)n_in; (void)out_size; (void)d_ws; (void)ws_size;
    const float* nw  = (const float*)d_in[0];
    const float* ew  = (const float*)d_in[1];
    const int*   Ag1 = (const int*)d_in[2];
    const int*   Ag2 = (const int*)d_in[3];
    const int*   l1  = (const int*)d_in[4];
    const int*   l2  = (const int*)d_in[5];
    hipLaunchKernelGGL(ged_all, dim3(1), dim3(1024), 0, stream,
                       nw, ew, Ag1, Ag2, l1, l2, (float*)d_out);
}

// Round 4
// 14.124 us; speedup vs baseline: 2.6513x; 1.0194x over previous
//
#include <hip/hip_runtime.h>

#define NVAL 95
#define SINK_ITERS 10

// One-block GED forward, label-compressed, 4-phase:
//  Ph0: all global loads + direct table builds (CT/E0 per-cell from nw, ftab
//       from ew) + labs/diag loads + zero P/H
//  Ph1: ONE merged phase on disjoint waves:
//       wave0: ballot-based label counts -> 11x11 sinkhorn
//       waves 1..12.8: row-tracked histogram scan (A data already in regs)
//       lanes 832..927: diagonal hists
//  Ph2: Q1/R2 contractions
//  Ph3: final scalar reduction
__global__ __launch_bounds__(1024)
void ged_all(const float* __restrict__ nw, const float* __restrict__ ew,
             const int* __restrict__ Ag1, const int* __restrict__ Ag2,
             const int* __restrict__ lab1g, const int* __restrict__ lab2g,
             float* __restrict__ outp)
{
    __shared__ float CT[11 * 12];      // c(a,b), stride 12
    __shared__ float E0s[11 * 12];     // exp(-0.5 c)
    __shared__ float ftab[16];
    __shared__ int   labs1[96], labs2[96];
    __shared__ float cnt1f[12], cnt2f[12];
    __shared__ int   P1h[363], P2h[363];
    __shared__ int   H1[48], H2[48];
    __shared__ float Rs[12], Cs[12];
    __shared__ float Q1s[4 * 132], R2s[4 * 132];
    __shared__ float wred[16];

    const int tid = threadIdx.x;
    const int t   = tid - 64;                    // scanner chunk id
    const bool scanner = (t >= 0 && t < 753);    // waves 1..12.8

    // ================= Ph0: loads + tables + zeroing =================
    int4 a1r[3], a2r[3];
    if (scanner) {
        if (t < 752) {
            const int4* A14 = (const int4*)Ag1;
            const int4* A24 = (const int4*)Ag2;
            #pragma unroll
            for (int r = 0; r < 3; ++r) { a1r[r] = A14[3 * t + r]; a2r[r] = A24[3 * t + r]; }
        } else {   // last chunk: single valid element 9024 (avoid OOB int4)
            a1r[0] = make_int4(Ag1[9024], 0, 0, 0);
            a2r[0] = make_int4(Ag2[9024], 0, 0, 0);
            a1r[1] = a1r[2] = a2r[1] = a2r[2] = make_int4(0, 0, 0, 0);
        }
        for (int i = t; i < 822; i += 753) {     // zero P1h|P2h|H1|H2
            if (i < 363) P1h[i] = 0;
            else if (i < 726) P2h[i - 363] = 0;
            else if (i < 774) H1[i - 726] = 0;
            else H2[i - 774] = 0;
        }
    }
    int d1v = 0, d2v = 0, myl1 = 0, myl2 = 0;
    if (tid >= 832 && tid < 928) {               // labels + adjacency diagonals
        int u = tid - 832;
        myl1 = (u < NVAL) ? lab1g[u] : 10;
        myl2 = (u < NVAL) ? lab2g[u] : 10;
        labs1[u] = myl1; labs2[u] = myl2;
        if (u < NVAL) { d1v = Ag1[u * 96]; d2v = Ag2[u * 96]; }   // u*95+u
    }
    {   // CT/E0 cells: lanes 928..1023 -> 0..95, lanes 0..24 -> 96..120
        int cell = (tid >= 928) ? (tid - 928) : ((tid < 25) ? 96 + tid : -1);
        if (cell >= 0) {
            int a = cell / 11, b = cell - a * 11;
            float c;
            if (a == b) c = 0.f;                         // diag & (10,10)
            else if (a < 10 && b < 10) {
                int mn = min(a, b), mx = max(a, b);
                int idx = mn * 9 - mn * (mn - 1) / 2 + (mx - mn - 1);
                c = fmaxf(nw[idx], 0.f);
            } else c = fmaxf(nw[45], 0.f);               // border ins/del
            CT[a * 12 + b]  = c;
            E0s[a * 12 + b] = expf(-0.5f * c);
        }
    }
    if (tid == 1023) {
        float e01 = fmaxf(ew[0], 0.f), e02 = fmaxf(ew[1], 0.f);
        float e12 = fmaxf(ew[2], 0.f), eid = fmaxf(ew[3], 0.f);
        ftab[0]  = 0.f; ftab[1]  = eid; ftab[2]  = eid; ftab[3]  = eid;
        ftab[4]  = eid; ftab[5]  = 0.f; ftab[6]  = e01; ftab[7]  = e02;
        ftab[8]  = eid; ftab[9]  = e01; ftab[10] = 0.f; ftab[11] = e12;
        ftab[12] = eid; ftab[13] = e02; ftab[14] = e12; ftab[15] = 0.f;
    }
    __syncthreads();   // ---- barrier A ----

    // ================= Ph1: scan || sinkhorn || diag hists =================
    if (tid < 64) {
        // ballot label counts (covers border: labs[95]=10 -> cnt[10]=1)
        int l = tid;
        int v1a = labs1[l],               v2a = labs2[l];
        int v1b = (l < 32) ? labs1[64 + l] : -1;
        int v2b = (l < 32) ? labs2[64 + l] : -1;
        float c1v = 0.f, c2v = 0.f;
        #pragma unroll
        for (int a = 0; a < 11; ++a) {
            int n1 = __popcll(__ballot(v1a == a)) + __popcll(__ballot(v1b == a));
            int n2 = __popcll(__ballot(v2a == a)) + __popcll(__ballot(v2b == a));
            if (l == a) { c1v = (float)n1; c2v = (float)n2; }
        }
        if (l < 11) { cnt1f[l] = c1v; cnt2f[l] = c2v; }
        // 11x11 sinkhorn, shuffle-only
        int ll = (l < 11) ? l : 0;
        float ecrow[11], eccol[11];
        #pragma unroll
        for (int b = 0; b < 11; ++b) ecrow[b] = E0s[ll * 12 + b] * __shfl(c2v, b, 64);
        #pragma unroll
        for (int a = 0; a < 11; ++a) eccol[a] = E0s[a * 12 + ll] * __shfl(c1v, a, 64);
        float Rv = 1.f, Cv = 1.f;
        for (int it = 0; it < SINK_ITERS; ++it) {
            float s = 0.f;
            #pragma unroll
            for (int b = 0; b < 11; ++b) s += ecrow[b] * __shfl(Cv, b, 64);
            Rv = (l == 10) ? 1.f : 1.f / s;
            float s2 = 0.f;
            #pragma unroll
            for (int a = 0; a < 11; ++a) s2 += eccol[a] * __shfl(Rv, a, 64);
            Cv = (l == 10) ? 1.f : 1.f / s2;
        }
        if (l < 11) { Rs[l] = Rv; Cs[l] = Cv; }
    }
    if (tid >= 832 && tid < 928) {
        int u = tid - 832;
        if (u < NVAL) {
            atomicAdd(&H1[d1v * 12 + myl1], 1);
            atomicAdd(&H2[d2v * 12 + myl2], 1);
        }
        // border diag (u=95, e=0, lab=10) added as a constant in Ph3
    }
    if (scanner) {
        // row-tracked chunk: elements [12t, 12t+12) cross <= 1 row boundary
        int base = t * 12;
        int i0 = base / 95;
        int j0 = base - i0 * 95;
        int rem = 95 - j0;                       // elements left in row i0
        int i1 = (i0 < 95) ? i0 + 1 : 95;
        int la1 = labs1[i0] * 11, lb1 = labs1[i1] * 11;
        int la2 = labs2[i0] * 11, lb2 = labs2[i1] * 11;
        int vals1[12] = { a1r[0].x, a1r[0].y, a1r[0].z, a1r[0].w,
                          a1r[1].x, a1r[1].y, a1r[1].z, a1r[1].w,
                          a1r[2].x, a1r[2].y, a1r[2].z, a1r[2].w };
        int vals2[12] = { a2r[0].x, a2r[0].y, a2r[0].z, a2r[0].w,
                          a2r[1].x, a2r[1].y, a2r[1].z, a2r[1].w,
                          a2r[2].x, a2r[2].y, a2r[2].z, a2r[2].w };
        #pragma unroll
        for (int q = 0; q < 12; ++q) {
            bool ok  = (base + q) < 9025;
            bool sec = q >= rem;
            int  j   = sec ? (q - rem) : (j0 + q);
            int  u1  = labs1[j], u2 = labs2[j];
            int  v1  = ok ? vals1[q] : 0;
            int  v2  = ok ? vals2[q] : 0;
            if (v1) atomicAdd(&P1h[(v1 - 1) * 121 + (sec ? lb1 : la1) + u1], 1);
            if (v2) atomicAdd(&P2h[(v2 - 1) * 121 + (sec ? lb2 : la2) + u2], 1);
        }
    }
    __syncthreads();   // ---- barrier B ----

    // ================= Ph2: Q1 / R2 contractions =================
    if (tid < 484) {
        int e = tid / 121, ab = tid - e * 121, a = ab / 11, b = ab - a * 11;
        float s = 0.f;
        #pragma unroll
        for (int a2 = 0; a2 < 11; ++a2) {
            int aa = a * 11 + a2;
            float p = (e == 0)
                ? cnt1f[a] * cnt1f[a2] - (float)(P1h[aa] + P1h[121 + aa] + P1h[242 + aa])
                : (float)P1h[(e - 1) * 121 + aa];
            s += p * E0s[a2 * 12 + b] * Rs[a2];
        }
        Q1s[e * 132 + a * 12 + b] = s * Cs[b];
    }
    if (tid >= 512 && tid < 996) {
        int tt = tid - 512;
        int e = tt / 121, ab = tt - e * 121, a = ab / 11, b = ab - a * 11;
        float s = 0.f;
        #pragma unroll
        for (int b2 = 0; b2 < 11; ++b2) {
            int bb = b * 11 + b2;
            float p = (e == 0)
                ? cnt2f[b] * cnt2f[b2] - (float)(P2h[bb] + P2h[121 + bb] + P2h[242 + bb])
                : (float)P2h[(e - 1) * 121 + bb];
            s += p * E0s[a * 12 + b2] * Cs[b2];
        }
        R2s[e * 132 + a * 12 + b] = s * Rs[a];
    }
    __syncthreads();   // ---- barrier C ----

    // ================= Ph3: final scalar =================
    float x = 0.f;
    if (tid < 968) {       // 2 of 1936 (e1,e2,a,b) terms each
        #pragma unroll
        for (int r = 0; r < 2; ++r) {
            int tt = tid + r * 968;
            int p = tt / 121, ab = tt - p * 121;
            int e1 = p >> 2, e2 = p & 3;
            int a = ab / 11, b = ab - a * 11;
            float f  = ftab[p];
            float tv = E0s[a * 12 + b] * Rs[a] * Cs[b];
            float h1 = (float)H1[e1 * 12 + a] + ((e1 == 0 && a == 10) ? 1.f : 0.f);
            float h2 = (float)H2[e2 * 12 + b] + ((e2 == 0 && b == 10) ? 1.f : 0.f);
            x += 0.5f * f * (Q1s[e1 * 132 + a * 12 + b] * R2s[e2 * 132 + a * 12 + b]
                             - h1 * h2 * tv * tv);
        }
    }
    if (tid < 121) {       // cv = c . v
        int a = tid / 11, b = tid - a * 11;
        x += cnt1f[a] * cnt2f[b] * CT[a * 12 + b] * E0s[a * 12 + b] * Rs[a] * Cs[b];
    }
    #pragma unroll
    for (int off = 32; off > 0; off >>= 1) x += __shfl_down(x, off, 64);
    if ((tid & 63) == 0) wred[tid >> 6] = x;
    __syncthreads();   // ---- barrier D ----
    if (tid == 0) {
        float s = 0.f;
        #pragma unroll
        for (int w = 0; w < 16; ++w) s += wred[w];
        outp[0] = s;
    }
}

extern "C" void kernel_launch(void* const* d_in, const int* in_sizes, int n_in,
                              void* d_out, int out_size, void* d_ws, size_t ws_size,
                              hipStream_t stream)
{
    (void)in_sizes; (void)n_in; (void)out_size; (void)d_ws; (void)ws_size;
    const float* nw  = (const float*)d_in[0];
    const float* ew  = (const float*)d_in[1];
    const int*   Ag1 = (const int*)d_in[2];
    const int*   Ag2 = (const int*)d_in[3];
    const int*   l1  = (const int*)d_in[4];
    const int*   l2  = (const int*)d_in[5];
    hipLaunchKernelGGL(ged_all, dim3(1), dim3(1024), 0, stream,
                       nw, ew, Ag1, Ag2, l1, l2, (float*)d_out);
}